// Round 5
// baseline (319.807 us; speedup 1.0000x reference)
//
#include <hip/hip_runtime.h>
#include <hip/hip_bf16.h>
#include <math.h>

#define H 1024
#define F 3584
#define F2 7168
#define NE 8
#define T 1024

typedef __attribute__((ext_vector_type(4))) float f32x4;
typedef __attribute__((ext_vector_type(8))) short bf16x8;
typedef __attribute__((ext_vector_type(2))) unsigned u32x2;
typedef __attribute__((ext_vector_type(4))) unsigned u32x4;

__device__ inline short f2bf(float f) {
  union { float f; unsigned u; } v; v.f = f;
  unsigned r = (v.u + 0x7FFFu + ((v.u >> 16) & 1u)) >> 16;
  return (short)r;
}

__device__ inline unsigned pkbf(float a, float b) {
  unsigned r;
  asm("v_cvt_pk_bf16_f32 %0, %1, %2" : "=v"(r) : "v"(a), "v"(b));
  return r;
}

// LDS bf16 tile, col-major-k, BK=32 (64 B per column), bank-uniform swizzle.
// byte(c,k) = c*64 + (2k ^ ((c>>2)&3)<<4). XOR bits 4-5 only -> 8/16B chunks
// stay contiguous; frag b128 reads hit 8 words/bank (floor), writes ~2-way.
__device__ inline int soff32(int c, int k) {
  return c * 64 + ((k << 1) ^ (((c >> 2) & 3) << 4));
}

// ---------------- router: fp64 logits, top-2 ----------------
__global__ __launch_bounds__(64) void router_k(
    const float* __restrict__ x, const float* __restrict__ gw,
    float* __restrict__ logits, int* __restrict__ cnt,
    int* __restrict__ tok_e, int* __restrict__ tok_r, float* __restrict__ tok_w)
{
  int t = blockIdx.x, l = threadIdx.x;
  const float* xr = x + (size_t)t * H;
  double acc[NE];
  #pragma unroll
  for (int e = 0; e < NE; ++e) acc[e] = 0.0;
  for (int j = 0; j < H / 64; ++j) {
    int h = j * 64 + l;
    float xv = xr[h];
    #pragma unroll
    for (int e = 0; e < NE; ++e) acc[e] += (double)xv * (double)gw[e * H + h];
  }
  #pragma unroll
  for (int off = 32; off >= 1; off >>= 1) {
    #pragma unroll
    for (int e = 0; e < NE; ++e) acc[e] += __shfl_down(acc[e], off, 64);
  }
  if (l == 0) {
    float lg[NE];
    #pragma unroll
    for (int e = 0; e < NE; ++e) { lg[e] = (float)acc[e]; logits[t * NE + e] = lg[e]; }
    int i0 = 0;
    for (int e = 1; e < NE; ++e) if (lg[e] > lg[i0]) i0 = e;
    int i1 = (i0 == 0) ? 1 : 0;
    for (int e = 0; e < NE; ++e) if (e != i0 && lg[e] > lg[i1]) i1 = e;
    float w0 = 1.f / (1.f + expf(lg[i1] - lg[i0]));
    float w1 = 1.f / (1.f + expf(lg[i0] - lg[i1]));
    int r0 = atomicAdd(&cnt[i0], 1);
    int r1 = atomicAdd(&cnt[i1], 1);
    tok_e[2 * t] = i0;     tok_r[2 * t] = r0;     tok_w[2 * t] = w0;
    tok_e[2 * t + 1] = i1; tok_r[2 * t + 1] = r1; tok_w[2 * t + 1] = w1;
  }
}

// ---------------- scan + gather list ----------------
__global__ __launch_bounds__(1024) void build_k(
    const int* __restrict__ cnt, int* __restrict__ base,
    const int* __restrict__ tok_e, const int* __restrict__ tok_r,
    const float* __restrict__ tok_w, int* __restrict__ gtok, float* __restrict__ gws)
{
  __shared__ int sb[NE];
  if (threadIdx.x == 0) {
    int s = 0;
    for (int e = 0; e < NE; ++e) { sb[e] = s; base[e] = s; s += cnt[e]; }
  }
  __syncthreads();
  int t = threadIdx.x;
  #pragma unroll
  for (int k = 0; k < 2; ++k) {
    int e = tok_e[2 * t + k];
    int slot = sb[e] + tok_r[2 * t + k];
    gtok[slot] = t;
    gws[slot] = tok_w[2 * t + k];
  }
}

// ---------------- ffn1: M=64, N=256 (128 gate + 128 up), BK=32, 2-deep ----------------
__global__ __launch_bounds__(256, 2) void ffn1_k(
    const float* __restrict__ x, const float* __restrict__ wgu,
    const int* __restrict__ cnt, const int* __restrict__ base,
    const int* __restrict__ gtok, unsigned short* __restrict__ act)
{
  // 3584 blocks = 8 XCD * 448 (= 16 mB * 28 p = one expert per XCD), mB fastest
  int wg = (blockIdx.x & 7) * 448 + (blockIdx.x >> 3);
  int mB = wg & 15;
  int rest = wg >> 4;
  int e = rest / 28, p = rest % 28;
  int n = cnt[e];
  int m0 = mB * 64;
  if (m0 >= n) return;
  int sb = base[e];
  int tid = threadIdx.x;
  int wv = tid >> 6, l = tid & 63, lr = l & 15, lg = l >> 4;

  __shared__ __align__(16) unsigned char smem[40960];
  unsigned char* sB0 = smem;              // 16 KB: 256 cols x 32 k bf16
  unsigned char* sB1 = smem + 16384;
  unsigned char* sA0 = smem + 32768;      // 4 KB: 64 rows x 32 k bf16
  unsigned char* sA1 = smem + 36864;

  // B staging: thread -> 4 cols (bc4..+3) x 8 k-rows (8*bko..+8)
  int bc4 = (tid & 63) * 4;
  int bko = tid >> 6;
  int gc = (bc4 < 128) ? (p * 128 + bc4) : (F + p * 128 + (bc4 - 128));
  const float* Bgp = wgu + (size_t)e * H * F2 + gc;
  int wB[4];
  #pragma unroll
  for (int j = 0; j < 4; ++j) wB[j] = soff32(bc4 + j, bko * 8);

  // A staging: thread -> 1 row x 8 k
  int ar = tid & 63, akq = tid >> 6;
  int asl = m0 + ar;
  int aslc = (asl < n) ? asl : (n - 1);
  const float* Agp = x + (size_t)gtok[sb + aslc] * H + akq * 8;
  int wA = soff32(ar, akq * 8);

  // fragment read offsets
  int rA[4], rB[4];
  #pragma unroll
  for (int mf = 0; mf < 4; ++mf) rA[mf] = soff32(mf * 16 + lr, lg * 8);
  #pragma unroll
  for (int c = 0; c < 4; ++c) {
    int col = ((c & 1) ? 16 : 0) + ((c & 2) ? 128 : 0) + wv * 32 + lr;
    rB[c] = soff32(col, lg * 8);
  }

  f32x4 acc[4][4];
  #pragma unroll
  for (int mf = 0; mf < 4; ++mf)
    #pragma unroll
    for (int c = 0; c < 4; ++c) acc[mf][c] = (f32x4)0.f;

  f32x4 bb0[8], bb1[8], aa0[2], aa1[2];

#define LD1(S, BB, AA) { \
    const float* bp = Bgp + (size_t)((S) * 32 + bko * 8) * F2; \
    BB[0] = *(const f32x4*)(bp);            BB[1] = *(const f32x4*)(bp + F2); \
    BB[2] = *(const f32x4*)(bp + 2 * F2);   BB[3] = *(const f32x4*)(bp + 3 * F2); \
    BB[4] = *(const f32x4*)(bp + 4 * F2);   BB[5] = *(const f32x4*)(bp + 5 * F2); \
    BB[6] = *(const f32x4*)(bp + 6 * F2);   BB[7] = *(const f32x4*)(bp + 7 * F2); \
    const float* ap = Agp + (S) * 32; \
    AA[0] = *(const f32x4*)(ap); AA[1] = *(const f32x4*)(ap + 4); }

#define PH1(BB, AA, sB, sA, SN, DO) { \
    _Pragma("unroll") for (int j = 0; j < 4; ++j) { \
      u32x4 w; w[0] = pkbf(BB[0][j], BB[1][j]); w[1] = pkbf(BB[2][j], BB[3][j]); \
      w[2] = pkbf(BB[4][j], BB[5][j]); w[3] = pkbf(BB[6][j], BB[7][j]); \
      *(u32x4*)((sB) + wB[j]) = w; } \
    { u32x4 w; w[0] = pkbf(AA[0][0], AA[0][1]); w[1] = pkbf(AA[0][2], AA[0][3]); \
      w[2] = pkbf(AA[1][0], AA[1][1]); w[3] = pkbf(AA[1][2], AA[1][3]); \
      *(u32x4*)((sA) + wA) = w; } \
    asm volatile("s_waitcnt lgkmcnt(0)" ::: "memory"); \
    __builtin_amdgcn_s_barrier(); \
    if (DO) { LD1(SN, BB, AA); } \
    bf16x8 bfr0 = *(const bf16x8*)((sB) + rB[0]); \
    bf16x8 bfr1 = *(const bf16x8*)((sB) + rB[1]); \
    bf16x8 bfr2 = *(const bf16x8*)((sB) + rB[2]); \
    bf16x8 bfr3 = *(const bf16x8*)((sB) + rB[3]); \
    _Pragma("unroll") for (int mf = 0; mf < 4; ++mf) { \
      bf16x8 af = *(const bf16x8*)((sA) + rA[mf]); \
      acc[mf][0] = __builtin_amdgcn_mfma_f32_16x16x32_bf16(af, bfr0, acc[mf][0], 0, 0, 0); \
      acc[mf][1] = __builtin_amdgcn_mfma_f32_16x16x32_bf16(af, bfr1, acc[mf][1], 0, 0, 0); \
      acc[mf][2] = __builtin_amdgcn_mfma_f32_16x16x32_bf16(af, bfr2, acc[mf][2], 0, 0, 0); \
      acc[mf][3] = __builtin_amdgcn_mfma_f32_16x16x32_bf16(af, bfr3, acc[mf][3], 0, 0, 0); } }

  LD1(0, bb0, aa0);
  LD1(1, bb1, aa1);

  for (int it = 0; it < 16; ++it) {
    PH1(bb0, aa0, sB0, sA0, 2 * it + 2, (it < 15));
    PH1(bb1, aa1, sB1, sA1, 2 * it + 3, (it < 15));
  }
#undef LD1
#undef PH1

  // epilogue: silu(gate)*up; gate = acc[mf][g], up = acc[mf][g+2]
  #pragma unroll
  for (int mf = 0; mf < 4; ++mf) {
    #pragma unroll
    for (int g = 0; g < 2; ++g) {
      int fcol = p * 128 + wv * 32 + g * 16 + lr;
      #pragma unroll
      for (int r = 0; r < 4; ++r) {
        int sl = m0 + mf * 16 + lg * 4 + r;
        if (sl < n) {
          float gg = acc[mf][g][r], u = acc[mf][g + 2][r];
          act[(size_t)(sb + sl) * F + fcol] = (unsigned short)f2bf(gg / (1.f + expf(-gg)) * u);
        }
      }
    }
  }
}

// ---------------- ffn2: M=64, N=128, BK=32, K-split x2 (56 phases), 2-deep ----------------
__global__ __launch_bounds__(256, 2) void ffn2_k(
    const unsigned short* __restrict__ act, const float* __restrict__ wd,
    const int* __restrict__ cnt, const int* __restrict__ base,
    const int* __restrict__ gtok, const float* __restrict__ gws,
    float* __restrict__ out)
{
  // 2048 blocks = 8 XCD * 256 (= 16 mB * 8 p * 2 kh = one expert per XCD)
  int wg = (blockIdx.x & 7) * 256 + (blockIdx.x >> 3);
  int mB = wg & 15;
  int rest = wg >> 4;
  int p = rest & 7;
  int khE = rest >> 3;
  int kh = khE & 1, e = khE >> 1;
  int n = cnt[e];
  int m0 = mB * 64;
  if (m0 >= n) return;
  int sb = base[e];
  int tid = threadIdx.x;
  int wv = tid >> 6, l = tid & 63, lr = l & 15, lg = l >> 4;
  const int kbase = kh * 1792;

  __shared__ __align__(16) unsigned char smem[24576];
  unsigned char* sB0 = smem;              // 8 KB: 128 cols x 32 k
  unsigned char* sB1 = smem + 8192;
  unsigned char* sA0 = smem + 16384;      // 4 KB
  unsigned char* sA1 = smem + 20480;

  // B staging: thread -> 4 cols x 4 k-rows (4*bkq..+4)
  int bc4 = (tid & 31) * 4;
  int bkq = tid >> 5;
  const float* Bgp = wd + (size_t)e * F * H + (size_t)kbase * H + p * 128 + bc4;
  int wB[4];
  #pragma unroll
  for (int j = 0; j < 4; ++j) wB[j] = soff32(bc4 + j, bkq * 4);

  // A staging: act is bf16 already — direct b128 global->reg->LDS
  int ar = tid & 63, akq = tid >> 6;
  int asl = m0 + ar;
  int aslc = (asl < n) ? asl : (n - 1);
  const unsigned short* Agp = act + (size_t)(sb + aslc) * F + kbase + akq * 8;
  int wA = soff32(ar, akq * 8);

  int rA[4], rB[2];
  #pragma unroll
  for (int mf = 0; mf < 4; ++mf) rA[mf] = soff32(mf * 16 + lr, lg * 8);
  #pragma unroll
  for (int c = 0; c < 2; ++c) rB[c] = soff32(wv * 32 + c * 16 + lr, lg * 8);

  f32x4 acc[4][2];
  #pragma unroll
  for (int mf = 0; mf < 4; ++mf) { acc[mf][0] = (f32x4)0.f; acc[mf][1] = (f32x4)0.f; }

  f32x4 bb0[4], bb1[4];
  bf16x8 aa0, aa1;

#define LD2(S, BB, AA) { \
    const float* bp = Bgp + (size_t)((S) * 32 + bkq * 4) * H; \
    BB[0] = *(const f32x4*)(bp);           BB[1] = *(const f32x4*)(bp + H); \
    BB[2] = *(const f32x4*)(bp + 2 * H);   BB[3] = *(const f32x4*)(bp + 3 * H); \
    AA = *(const bf16x8*)(Agp + (S) * 32); }

#define PH2(BB, AA, sB, sA, SN, DO) { \
    _Pragma("unroll") for (int j = 0; j < 4; ++j) { \
      u32x2 w; w[0] = pkbf(BB[0][j], BB[1][j]); w[1] = pkbf(BB[2][j], BB[3][j]); \
      *(u32x2*)((sB) + wB[j]) = w; } \
    *(bf16x8*)((sA) + wA) = AA; \
    asm volatile("s_waitcnt lgkmcnt(0)" ::: "memory"); \
    __builtin_amdgcn_s_barrier(); \
    if (DO) { LD2(SN, BB, AA); } \
    bf16x8 bfr0 = *(const bf16x8*)((sB) + rB[0]); \
    bf16x8 bfr1 = *(const bf16x8*)((sB) + rB[1]); \
    _Pragma("unroll") for (int mf = 0; mf < 4; ++mf) { \
      bf16x8 af = *(const bf16x8*)((sA) + rA[mf]); \
      acc[mf][0] = __builtin_amdgcn_mfma_f32_16x16x32_bf16(af, bfr0, acc[mf][0], 0, 0, 0); \
      acc[mf][1] = __builtin_amdgcn_mfma_f32_16x16x32_bf16(af, bfr1, acc[mf][1], 0, 0, 0); } }

  LD2(0, bb0, aa0);
  LD2(1, bb1, aa1);

  for (int it = 0; it < 28; ++it) {
    PH2(bb0, aa0, sB0, sA0, 2 * it + 2, (it < 27));
    PH2(bb1, aa1, sB1, sA1, 2 * it + 3, (it < 27));
  }
#undef LD2
#undef PH2

  #pragma unroll
  for (int mf = 0; mf < 4; ++mf) {
    #pragma unroll
    for (int c = 0; c < 2; ++c) {
      int col = p * 128 + wv * 32 + c * 16 + lr;
      #pragma unroll
      for (int r = 0; r < 4; ++r) {
        int sl = m0 + mf * 16 + lg * 4 + r;
        if (sl < n) {
          int slot = sb + sl;
          atomicAdd(&out[(size_t)gtok[slot] * H + col], gws[slot] * acc[mf][c][r]);
        }
      }
    }
  }
}

extern "C" void kernel_launch(void* const* d_in, const int* in_sizes, int n_in,
                              void* d_out, int out_size, void* d_ws, size_t ws_size,
                              hipStream_t stream)
{
  const float* x   = (const float*)d_in[0];
  const float* gw  = (const float*)d_in[1];
  const float* wgu = (const float*)d_in[2];
  const float* wdn = (const float*)d_in[3];
  float* out = (float*)d_out;
  float* logits = out + (size_t)T * H;

  char* w = (char*)d_ws;
  int*   cnt = (int*)(w);
  int*   bs  = (int*)(w + 32);
  int*   te  = (int*)(w + 64);
  int*   tr  = (int*)(w + 64 + 8192);
  float* tw  = (float*)(w + 64 + 16384);
  int*   gt  = (int*)(w + 64 + 24576);
  float* gwt = (float*)(w + 64 + 32768);
  unsigned short* act = (unsigned short*)(w + 65536);  // 2048 x 3584 bf16

  hipMemsetAsync(d_out, 0, (size_t)T * H * sizeof(float), stream);
  hipMemsetAsync(cnt, 0, NE * sizeof(int), stream);
  router_k<<<T, 64, 0, stream>>>(x, gw, logits, cnt, te, tr, tw);
  build_k<<<1, 1024, 0, stream>>>(cnt, bs, te, tr, tw, gt, gwt);
  ffn1_k<<<3584, 256, 0, stream>>>(x, wgu, cnt, bs, gt, act);
  ffn2_k<<<2048, 256, 0, stream>>>(act, wdn, cnt, bs, gt, gwt, out);
}

// Round 7
// 277.261 us; speedup vs baseline: 1.1535x; 1.1535x over previous
//
#include <hip/hip_runtime.h>
#include <hip/hip_bf16.h>
#include <math.h>

#define H 1024
#define F 3584
#define F2 7168
#define NE 8
#define T 1024

typedef __attribute__((ext_vector_type(4))) float f32x4;
typedef __attribute__((ext_vector_type(8))) short bf16x8;
typedef __attribute__((ext_vector_type(4))) unsigned u32x4;

__device__ inline short f2bf(float f) {
  union { float f; unsigned u; } v; v.f = f;
  unsigned r = (v.u + 0x7FFFu + ((v.u >> 16) & 1u)) >> 16;
  return (short)r;
}

__device__ inline unsigned pkbf(float a, float b) {
  unsigned r;
  asm("v_cvt_pk_bf16_f32 %0, %1, %2" : "=v"(r) : "v"(a), "v"(b));
  return r;
}

// async global->LDS, 16B per lane. LDS dest = wave-uniform base + lane*16.
__device__ inline void gload16(const void* g, void* l) {
  __builtin_amdgcn_global_load_lds(
      (const __attribute__((address_space(1))) void*)g,
      (__attribute__((address_space(3))) void*)l, 16, 0, 0);
}

// ---------------- router: fp64 logits, top-2 ----------------
__global__ __launch_bounds__(64) void router_k(
    const float* __restrict__ x, const float* __restrict__ gw,
    float* __restrict__ logits, int* __restrict__ cnt,
    int* __restrict__ tok_e, int* __restrict__ tok_r, float* __restrict__ tok_w)
{
  int t = blockIdx.x, l = threadIdx.x;
  const float* xr = x + (size_t)t * H;
  double acc[NE];
  #pragma unroll
  for (int e = 0; e < NE; ++e) acc[e] = 0.0;
  for (int j = 0; j < H / 64; ++j) {
    int h = j * 64 + l;
    float xv = xr[h];
    #pragma unroll
    for (int e = 0; e < NE; ++e) acc[e] += (double)xv * (double)gw[e * H + h];
  }
  #pragma unroll
  for (int off = 32; off >= 1; off >>= 1) {
    #pragma unroll
    for (int e = 0; e < NE; ++e) acc[e] += __shfl_down(acc[e], off, 64);
  }
  if (l == 0) {
    float lg[NE];
    #pragma unroll
    for (int e = 0; e < NE; ++e) { lg[e] = (float)acc[e]; logits[t * NE + e] = lg[e]; }
    int i0 = 0;
    for (int e = 1; e < NE; ++e) if (lg[e] > lg[i0]) i0 = e;
    int i1 = (i0 == 0) ? 1 : 0;
    for (int e = 0; e < NE; ++e) if (e != i0 && lg[e] > lg[i1]) i1 = e;
    float w0 = 1.f / (1.f + expf(lg[i1] - lg[i0]));
    float w1 = 1.f / (1.f + expf(lg[i0] - lg[i1]));
    int r0 = atomicAdd(&cnt[i0], 1);
    int r1 = atomicAdd(&cnt[i1], 1);
    tok_e[2 * t] = i0;     tok_r[2 * t] = r0;     tok_w[2 * t] = w0;
    tok_e[2 * t + 1] = i1; tok_r[2 * t + 1] = r1; tok_w[2 * t + 1] = w1;
  }
}

// ---------------- scan + gather list ----------------
__global__ __launch_bounds__(1024) void build_k(
    const int* __restrict__ cnt, int* __restrict__ base,
    const int* __restrict__ tok_e, const int* __restrict__ tok_r,
    const float* __restrict__ tok_w, int* __restrict__ gtok, float* __restrict__ gws)
{
  __shared__ int sb[NE];
  if (threadIdx.x == 0) {
    int s = 0;
    for (int e = 0; e < NE; ++e) { sb[e] = s; base[e] = s; s += cnt[e]; }
  }
  __syncthreads();
  int t = threadIdx.x;
  #pragma unroll
  for (int k = 0; k < 2; ++k) {
    int e = tok_e[2 * t + k];
    int slot = sb[e] + tok_r[2 * t + k];
    gtok[slot] = t;
    gws[slot] = tok_w[2 * t + k];
  }
}

// ---------------- ffn1: M=64, N=256 (128g+128u), BK=32, global_load_lds ----------------
// LDS (single buffer, 40KB): B fp32 [k=32][c=256] rows 1KB, chunk-swizzled
// (chunk_data = chunk_lin ^ (k>>3)); A fp32 [row=64][k=32] rows 128B, seg-swizzled
// (seg_data = seg_lin ^ (row&7)). Swizzles applied via per-lane SOURCE address
// (LDS writes stay linear for the DMA), matching XOR on read side.
__global__ __launch_bounds__(256, 4) void ffn1_k(
    const float* __restrict__ x, const float* __restrict__ wgu,
    const int* __restrict__ cnt, const int* __restrict__ base,
    const int* __restrict__ gtok, unsigned short* __restrict__ act)
{
  // 3584 blocks = 8 XCD * 448 (one expert per XCD), mB fastest for L2 dedup
  int wg = (blockIdx.x & 7) * 448 + (blockIdx.x >> 3);
  int mB = wg & 15;
  int rest = wg >> 4;                 // 0..223
  int e = rest / 28, p = rest % 28;
  int n = cnt[e];
  int m0 = mB * 64;
  if (m0 >= n) return;
  int sb = base[e];
  int tid = threadIdx.x;
  int wv = tid >> 6, lane = tid & 63, lr = lane & 15, lg = lane >> 4;

  __shared__ __align__(16) float smem[10240];   // 32KB B + 8KB A
  char* sBb = (char*)smem;
  char* sAb = (char*)(smem + 8192);

  // ---- B staging: wave wv stages k-rows wv*8+j (j=0..7), 1KB row per issue ----
  int bchunk = lane ^ wv;             // source chunk (pre-swizzle: gg = k>>3 = wv)
  int tc = bchunk * 4;
  int gc = (tc < 128) ? (p * 128 + tc) : (F + p * 128 + (tc - 128));
  const float* Bsrc = wgu + (size_t)e * H * F2 + (size_t)(wv * 8) * F2 + gc;

  // ---- A staging: wave wv stages rows wv*16..+16 in 2 issues ----
  int ar0 = wv * 16 + (lane >> 3);
  int ar1 = ar0 + 8;
  int as0 = (lane & 7) ^ (ar0 & 7);
  int as1 = (lane & 7) ^ (ar1 & 7);
  int sl0 = m0 + ar0; if (sl0 >= n) sl0 = n - 1;
  int sl1 = m0 + ar1; if (sl1 >= n) sl1 = n - 1;
  const float* Asrc0 = x + (size_t)gtok[sb + sl0] * H + as0 * 4;
  const float* Asrc1 = x + (size_t)gtok[sb + sl1] * H + as1 * 4;

  // ---- read offsets ----
  int rboff[4];
  #pragma unroll
  for (int cf = 0; cf < 4; ++cf) {
    int col = ((cf < 2) ? (wv * 32 + cf * 16) : (128 + wv * 32 + (cf - 2) * 16)) + lr;
    rboff[cf] = lg * 8 * 1024 + ((col * 4) ^ (lg << 4));
  }
  int raoff0[4], raoff1[4];
  #pragma unroll
  for (int mf = 0; mf < 4; ++mf) {
    int row = mf * 16 + lr;
    raoff0[mf] = row * 128 + ((((lg << 1) | 0) ^ (row & 7)) << 4);
    raoff1[mf] = row * 128 + ((((lg << 1) | 1) ^ (row & 7)) << 4);
  }

  f32x4 acc[4][4];
  #pragma unroll
  for (int mf = 0; mf < 4; ++mf)
    #pragma unroll
    for (int cf = 0; cf < 4; ++cf) acc[mf][cf] = (f32x4)0.f;

  for (int s = 0; s < 32; ++s) {
    const float* bs = Bsrc + (size_t)s * 32 * F2;
    #pragma unroll
    for (int j = 0; j < 8; ++j)
      gload16(bs + (size_t)j * F2, sBb + (wv * 8 + j) * 1024);
    gload16(Asrc0 + s * 32, sAb + (wv * 16) * 128);
    gload16(Asrc1 + s * 32, sAb + (wv * 16 + 8) * 128);
    asm volatile("s_waitcnt vmcnt(0)" ::: "memory");
    __builtin_amdgcn_s_barrier();
    asm volatile("" ::: "memory");

    bf16x8 bfr[4];
    #pragma unroll
    for (int cf = 0; cf < 4; ++cf) {
      float f0 = *(const float*)(sBb + rboff[cf]);
      float f1 = *(const float*)(sBb + rboff[cf] + 1024);
      float f2 = *(const float*)(sBb + rboff[cf] + 2048);
      float f3 = *(const float*)(sBb + rboff[cf] + 3072);
      float f4 = *(const float*)(sBb + rboff[cf] + 4096);
      float f5 = *(const float*)(sBb + rboff[cf] + 5120);
      float f6 = *(const float*)(sBb + rboff[cf] + 6144);
      float f7 = *(const float*)(sBb + rboff[cf] + 7168);
      union { u32x4 u; bf16x8 h; } cv;
      cv.u[0] = pkbf(f0, f1); cv.u[1] = pkbf(f2, f3);
      cv.u[2] = pkbf(f4, f5); cv.u[3] = pkbf(f6, f7);
      bfr[cf] = cv.h;
    }
    #pragma unroll
    for (int mf = 0; mf < 4; ++mf) {
      f32x4 a0 = *(const f32x4*)(sAb + raoff0[mf]);
      f32x4 a1 = *(const f32x4*)(sAb + raoff1[mf]);
      union { u32x4 u; bf16x8 h; } cv;
      cv.u[0] = pkbf(a0[0], a0[1]); cv.u[1] = pkbf(a0[2], a0[3]);
      cv.u[2] = pkbf(a1[0], a1[1]); cv.u[3] = pkbf(a1[2], a1[3]);
      bf16x8 af = cv.h;
      acc[mf][0] = __builtin_amdgcn_mfma_f32_16x16x32_bf16(af, bfr[0], acc[mf][0], 0, 0, 0);
      acc[mf][1] = __builtin_amdgcn_mfma_f32_16x16x32_bf16(af, bfr[1], acc[mf][1], 0, 0, 0);
      acc[mf][2] = __builtin_amdgcn_mfma_f32_16x16x32_bf16(af, bfr[2], acc[mf][2], 0, 0, 0);
      acc[mf][3] = __builtin_amdgcn_mfma_f32_16x16x32_bf16(af, bfr[3], acc[mf][3], 0, 0, 0);
    }
    asm volatile("s_waitcnt lgkmcnt(0)" ::: "memory");
    __builtin_amdgcn_s_barrier();
    asm volatile("" ::: "memory");
  }

  // epilogue: silu(gate)*up; gate cf 0..1, up cf 2..3
  #pragma unroll
  for (int mf = 0; mf < 4; ++mf) {
    #pragma unroll
    for (int g = 0; g < 2; ++g) {
      int fcol = p * 128 + wv * 32 + g * 16 + lr;
      #pragma unroll
      for (int r = 0; r < 4; ++r) {
        int sl = m0 + mf * 16 + lg * 4 + r;
        if (sl < n) {
          float gg = acc[mf][g][r], u = acc[mf][g + 2][r];
          act[(size_t)(sb + sl) * F + fcol] = (unsigned short)f2bf(gg / (1.f + expf(-gg)) * u);
        }
      }
    }
  }
}

// ---------------- ffn2: M=64, N=128, BK=32, K-split x4, global_load_lds ----------------
// LDS 20KB: B fp32 [k=32][c=128] rows 512B chunk-swizzled; A bf16 [row=64][k=32]
// rows 64B seg-swizzled (seg_data = seg_lin ^ (row&3)).
__global__ __launch_bounds__(256, 4) void ffn2_k(
    const unsigned short* __restrict__ act, const float* __restrict__ wd,
    const int* __restrict__ cnt, const int* __restrict__ base,
    const int* __restrict__ gtok, const float* __restrict__ gws,
    float* __restrict__ out)
{
  // 4096 blocks = 8 XCD * 512 (one expert per XCD): 16 mB * 8 p * 4 kh
  int wg = (blockIdx.x & 7) * 512 + (blockIdx.x >> 3);
  int mB = wg & 15;
  int rest = wg >> 4;                // 0..255
  int p = rest & 7;
  int kh = (rest >> 3) & 3;
  int e = rest >> 5;
  int n = cnt[e];
  int m0 = mB * 64;
  if (m0 >= n) return;
  int sb = base[e];
  int tid = threadIdx.x;
  int wv = tid >> 6, lane = tid & 63, lr = lane & 15, lg = lane >> 4;
  const int kbase = kh * 896;

  __shared__ __align__(16) char smem2[20480];
  char* sBb = smem2;                 // 16KB
  char* sAb = smem2 + 16384;         // 4KB

  // B staging: wave wv stages k-rows wv*8 .. +8 in 4 issues (2 rows/issue)
  int bchunk = (lane & 31) ^ wv;
  const float* Bsrc = wd + (size_t)e * F * H
                    + (size_t)(kbase + wv * 8 + (lane >> 5)) * H + p * 128 + bchunk * 4;

  // A staging: wave wv stages rows wv*16..+16 in 1 issue (4 lanes/row)
  int arow = wv * 16 + (lane >> 2);
  int aseg = (lane & 3) ^ (arow & 3);
  int asl = m0 + arow; if (asl >= n) asl = n - 1;
  const unsigned short* Asrc = act + (size_t)(sb + asl) * F + kbase + aseg * 8;

  int rboff[2];
  #pragma unroll
  for (int cf = 0; cf < 2; ++cf) {
    int col = wv * 32 + cf * 16 + lr;
    rboff[cf] = lg * 8 * 512 + ((col * 4) ^ (lg << 4));
  }
  int raoff[4];
  #pragma unroll
  for (int mf = 0; mf < 4; ++mf) {
    int row = mf * 16 + lr;
    raoff[mf] = row * 64 + ((lg ^ (row & 3)) << 4);
  }

  f32x4 acc[4][2];
  #pragma unroll
  for (int mf = 0; mf < 4; ++mf) { acc[mf][0] = (f32x4)0.f; acc[mf][1] = (f32x4)0.f; }

  for (int s = 0; s < 28; ++s) {
    const float* bs = Bsrc + (size_t)s * 32 * H;
    #pragma unroll
    for (int j = 0; j < 4; ++j)
      gload16(bs + (size_t)(2 * j) * H, sBb + (wv * 8 + 2 * j) * 512);
    gload16(Asrc + s * 32, sAb + wv * 16 * 64);
    asm volatile("s_waitcnt vmcnt(0)" ::: "memory");
    __builtin_amdgcn_s_barrier();
    asm volatile("" ::: "memory");

    bf16x8 bfr[2];
    #pragma unroll
    for (int cf = 0; cf < 2; ++cf) {
      float f0 = *(const float*)(sBb + rboff[cf]);
      float f1 = *(const float*)(sBb + rboff[cf] + 512);
      float f2 = *(const float*)(sBb + rboff[cf] + 1024);
      float f3 = *(const float*)(sBb + rboff[cf] + 1536);
      float f4 = *(const float*)(sBb + rboff[cf] + 2048);
      float f5 = *(const float*)(sBb + rboff[cf] + 2560);
      float f6 = *(const float*)(sBb + rboff[cf] + 3072);
      float f7 = *(const float*)(sBb + rboff[cf] + 3584);
      union { u32x4 u; bf16x8 h; } cv;
      cv.u[0] = pkbf(f0, f1); cv.u[1] = pkbf(f2, f3);
      cv.u[2] = pkbf(f4, f5); cv.u[3] = pkbf(f6, f7);
      bfr[cf] = cv.h;
    }
    #pragma unroll
    for (int mf = 0; mf < 4; ++mf) {
      bf16x8 af = *(const bf16x8*)(sAb + raoff[mf]);
      acc[mf][0] = __builtin_amdgcn_mfma_f32_16x16x32_bf16(af, bfr[0], acc[mf][0], 0, 0, 0);
      acc[mf][1] = __builtin_amdgcn_mfma_f32_16x16x32_bf16(af, bfr[1], acc[mf][1], 0, 0, 0);
    }
    asm volatile("s_waitcnt lgkmcnt(0)" ::: "memory");
    __builtin_amdgcn_s_barrier();
    asm volatile("" ::: "memory");
  }

  #pragma unroll
  for (int mf = 0; mf < 4; ++mf) {
    #pragma unroll
    for (int cf = 0; cf < 2; ++cf) {
      int col = p * 128 + wv * 32 + cf * 16 + lr;
      #pragma unroll
      for (int r = 0; r < 4; ++r) {
        int sl = m0 + mf * 16 + lg * 4 + r;
        if (sl < n) {
          int slot = sb + sl;
          atomicAdd(&out[(size_t)gtok[slot] * H + col], gws[slot] * acc[mf][cf][r]);
        }
      }
    }
  }
}

extern "C" void kernel_launch(void* const* d_in, const int* in_sizes, int n_in,
                              void* d_out, int out_size, void* d_ws, size_t ws_size,
                              hipStream_t stream)
{
  const float* x   = (const float*)d_in[0];
  const float* gw  = (const float*)d_in[1];
  const float* wgu = (const float*)d_in[2];
  const float* wdn = (const float*)d_in[3];
  float* out = (float*)d_out;
  float* logits = out + (size_t)T * H;

  char* w = (char*)d_ws;
  int*   cnt = (int*)(w);
  int*   bs  = (int*)(w + 32);
  int*   te  = (int*)(w + 64);
  int*   tr  = (int*)(w + 64 + 8192);
  float* tw  = (float*)(w + 64 + 16384);
  int*   gt  = (int*)(w + 64 + 24576);
  float* gwt = (float*)(w + 64 + 32768);
  unsigned short* act = (unsigned short*)(w + 65536);  // 2048 x 3584 bf16

  hipMemsetAsync(d_out, 0, (size_t)T * H * sizeof(float), stream);
  hipMemsetAsync(cnt, 0, NE * sizeof(int), stream);
  router_k<<<T, 64, 0, stream>>>(x, gw, logits, cnt, te, tr, tw);
  build_k<<<1, 1024, 0, stream>>>(cnt, bs, te, tr, tw, gt, gwt);
  ffn1_k<<<3584, 256, 0, stream>>>(x, wgu, cnt, bs, gt, act);
  ffn2_k<<<4096, 256, 0, stream>>>(act, wdn, cnt, bs, gt, gwt, out);
}

// Round 8
// 276.237 us; speedup vs baseline: 1.1577x; 1.0037x over previous
//
#include <hip/hip_runtime.h>
#include <hip/hip_bf16.h>
#include <math.h>

#define H 1024
#define F 3584
#define F2 7168
#define NE 8
#define T 1024

typedef __attribute__((ext_vector_type(4))) float f32x4;
typedef __attribute__((ext_vector_type(8))) short bf16x8;
typedef __attribute__((ext_vector_type(4))) unsigned u32x4;

__device__ inline short f2bf(float f) {
  union { float f; unsigned u; } v; v.f = f;
  unsigned r = (v.u + 0x7FFFu + ((v.u >> 16) & 1u)) >> 16;
  return (short)r;
}

__device__ inline unsigned pkbf(float a, float b) {
  unsigned r;
  asm("v_cvt_pk_bf16_f32 %0, %1, %2" : "=v"(r) : "v"(a), "v"(b));
  return r;
}

// async global->LDS, 16B per lane. LDS dest = wave-uniform base + lane*16.
__device__ inline void gload16(const void* g, void* l) {
  __builtin_amdgcn_global_load_lds(
      (const __attribute__((address_space(1))) void*)g,
      (__attribute__((address_space(3))) void*)l, 16, 0, 0);
}

// ---------------- router: fp64 logits, top-2 ----------------
__global__ __launch_bounds__(64) void router_k(
    const float* __restrict__ x, const float* __restrict__ gw,
    float* __restrict__ logits, int* __restrict__ cnt,
    int* __restrict__ tok_e, int* __restrict__ tok_r, float* __restrict__ tok_w)
{
  int t = blockIdx.x, l = threadIdx.x;
  const float* xr = x + (size_t)t * H;
  double acc[NE];
  #pragma unroll
  for (int e = 0; e < NE; ++e) acc[e] = 0.0;
  for (int j = 0; j < H / 64; ++j) {
    int h = j * 64 + l;
    float xv = xr[h];
    #pragma unroll
    for (int e = 0; e < NE; ++e) acc[e] += (double)xv * (double)gw[e * H + h];
  }
  #pragma unroll
  for (int off = 32; off >= 1; off >>= 1) {
    #pragma unroll
    for (int e = 0; e < NE; ++e) acc[e] += __shfl_down(acc[e], off, 64);
  }
  if (l == 0) {
    float lg[NE];
    #pragma unroll
    for (int e = 0; e < NE; ++e) { lg[e] = (float)acc[e]; logits[t * NE + e] = lg[e]; }
    int i0 = 0;
    for (int e = 1; e < NE; ++e) if (lg[e] > lg[i0]) i0 = e;
    int i1 = (i0 == 0) ? 1 : 0;
    for (int e = 0; e < NE; ++e) if (e != i0 && lg[e] > lg[i1]) i1 = e;
    float w0 = 1.f / (1.f + expf(lg[i1] - lg[i0]));
    float w1 = 1.f / (1.f + expf(lg[i0] - lg[i1]));
    int r0 = atomicAdd(&cnt[i0], 1);
    int r1 = atomicAdd(&cnt[i1], 1);
    tok_e[2 * t] = i0;     tok_r[2 * t] = r0;     tok_w[2 * t] = w0;
    tok_e[2 * t + 1] = i1; tok_r[2 * t + 1] = r1; tok_w[2 * t + 1] = w1;
  }
}

// ---------------- scan + gather list ----------------
__global__ __launch_bounds__(1024) void build_k(
    const int* __restrict__ cnt, int* __restrict__ base,
    const int* __restrict__ tok_e, const int* __restrict__ tok_r,
    const float* __restrict__ tok_w, int* __restrict__ gtok, float* __restrict__ gws)
{
  __shared__ int sb[NE];
  if (threadIdx.x == 0) {
    int s = 0;
    for (int e = 0; e < NE; ++e) { sb[e] = s; base[e] = s; s += cnt[e]; }
  }
  __syncthreads();
  int t = threadIdx.x;
  #pragma unroll
  for (int k = 0; k < 2; ++k) {
    int e = tok_e[2 * t + k];
    int slot = sb[e] + tok_r[2 * t + k];
    gtok[slot] = t;
    gws[slot] = tok_w[2 * t + k];
  }
}

// ---------------- ffn1: M=64, N=256 (128g+128u), BK=32, gload_lds, DBUF+counted vmcnt ----------------
// Per buffer (40KB): B fp32 [k=32][c=256] rows 1KB chunk-swizzled; A fp32 [row=64][k=32]
// rows 128B seg-swizzled. 2 buffers = 80KB -> 2 blocks/CU. Issue batch s+1 into the
// other buffer BEFORE waiting vmcnt(10) for batch s (T4: never drain to 0 mid-loop).
__global__ __launch_bounds__(256, 2) void ffn1_k(
    const float* __restrict__ x, const float* __restrict__ wgu,
    const int* __restrict__ cnt, const int* __restrict__ base,
    const int* __restrict__ gtok, unsigned short* __restrict__ act)
{
  // 3584 blocks = 8 XCD * 448 (one expert per XCD), mB fastest for L2 dedup
  int wg = (blockIdx.x & 7) * 448 + (blockIdx.x >> 3);
  int mB = wg & 15;
  int rest = wg >> 4;                 // 0..223
  int e = rest / 28, p = rest % 28;
  int n = cnt[e];
  int m0 = mB * 64;
  if (m0 >= n) return;
  int sb = base[e];
  int tid = threadIdx.x;
  int wv = tid >> 6, lane = tid & 63, lr = lane & 15, lg = lane >> 4;

  __shared__ __align__(16) char smem[81920];
  char* sB0 = smem;                   // 32KB
  char* sA0 = smem + 32768;           // 8KB
  char* sB1 = smem + 40960;           // 32KB
  char* sA1 = smem + 73728;           // 8KB

  // ---- B staging: wave wv stages k-rows wv*8+j (j=0..7), 1KB row per issue ----
  int bchunk = lane ^ wv;             // pre-swizzled source chunk (gg = k>>3 = wv)
  int tc = bchunk * 4;
  int gc = (tc < 128) ? (p * 128 + tc) : (F + p * 128 + (tc - 128));
  const float* Bsrc = wgu + (size_t)e * H * F2 + (size_t)(wv * 8) * F2 + gc;

  // ---- A staging: wave wv stages rows wv*16..+16 in 2 issues ----
  int ar0 = wv * 16 + (lane >> 3);
  int ar1 = ar0 + 8;
  int as0 = (lane & 7) ^ (ar0 & 7);
  int as1 = (lane & 7) ^ (ar1 & 7);
  int sl0 = m0 + ar0; if (sl0 >= n) sl0 = n - 1;
  int sl1 = m0 + ar1; if (sl1 >= n) sl1 = n - 1;
  const float* Asrc0 = x + (size_t)gtok[sb + sl0] * H + as0 * 4;
  const float* Asrc1 = x + (size_t)gtok[sb + sl1] * H + as1 * 4;

  // ---- read offsets ----
  int rboff[4];
  #pragma unroll
  for (int cf = 0; cf < 4; ++cf) {
    int col = ((cf < 2) ? (wv * 32 + cf * 16) : (128 + wv * 32 + (cf - 2) * 16)) + lr;
    rboff[cf] = lg * 8 * 1024 + ((col * 4) ^ (lg << 4));
  }
  int raoff0[4], raoff1[4];
  #pragma unroll
  for (int mf = 0; mf < 4; ++mf) {
    int row = mf * 16 + lr;
    raoff0[mf] = row * 128 + ((((lg << 1) | 0) ^ (row & 7)) << 4);
    raoff1[mf] = row * 128 + ((((lg << 1) | 1) ^ (row & 7)) << 4);
  }

  f32x4 acc[4][4];
  #pragma unroll
  for (int mf = 0; mf < 4; ++mf)
    #pragma unroll
    for (int cf = 0; cf < 4; ++cf) acc[mf][cf] = (f32x4)0.f;

#define ISSUE1(S, bB, bA) { \
    const float* bs_ = Bsrc + (size_t)(S) * 32 * F2; \
    _Pragma("unroll") for (int j = 0; j < 8; ++j) \
      gload16(bs_ + (size_t)j * F2, (bB) + (wv * 8 + j) * 1024); \
    gload16(Asrc0 + (S) * 32, (bA) + (wv * 16) * 128); \
    gload16(Asrc1 + (S) * 32, (bA) + (wv * 16 + 8) * 128); }

  ISSUE1(0, sB0, sA0);

  for (int s = 0; s < 32; ++s) {
    char* cB = (s & 1) ? sB1 : sB0;
    char* cA = (s & 1) ? sA1 : sA0;
    char* nB = (s & 1) ? sB0 : sB1;
    char* nA = (s & 1) ? sA0 : sA1;
    if (s + 1 < 32) {
      ISSUE1(s + 1, nB, nA);
      asm volatile("s_waitcnt vmcnt(10)" ::: "memory");   // batch s landed; s+1 in flight
    } else {
      asm volatile("s_waitcnt vmcnt(0)" ::: "memory");
    }
    __builtin_amdgcn_s_barrier();
    asm volatile("" ::: "memory");

    bf16x8 bfr[4];
    #pragma unroll
    for (int cf = 0; cf < 4; ++cf) {
      float f0 = *(const float*)(cB + rboff[cf]);
      float f1 = *(const float*)(cB + rboff[cf] + 1024);
      float f2 = *(const float*)(cB + rboff[cf] + 2048);
      float f3 = *(const float*)(cB + rboff[cf] + 3072);
      float f4 = *(const float*)(cB + rboff[cf] + 4096);
      float f5 = *(const float*)(cB + rboff[cf] + 5120);
      float f6 = *(const float*)(cB + rboff[cf] + 6144);
      float f7 = *(const float*)(cB + rboff[cf] + 7168);
      union { u32x4 u; bf16x8 h; } cv;
      cv.u[0] = pkbf(f0, f1); cv.u[1] = pkbf(f2, f3);
      cv.u[2] = pkbf(f4, f5); cv.u[3] = pkbf(f6, f7);
      bfr[cf] = cv.h;
    }
    #pragma unroll
    for (int mf = 0; mf < 4; ++mf) {
      f32x4 a0 = *(const f32x4*)(cA + raoff0[mf]);
      f32x4 a1 = *(const f32x4*)(cA + raoff1[mf]);
      union { u32x4 u; bf16x8 h; } cv;
      cv.u[0] = pkbf(a0[0], a0[1]); cv.u[1] = pkbf(a0[2], a0[3]);
      cv.u[2] = pkbf(a1[0], a1[1]); cv.u[3] = pkbf(a1[2], a1[3]);
      bf16x8 af = cv.h;
      acc[mf][0] = __builtin_amdgcn_mfma_f32_16x16x32_bf16(af, bfr[0], acc[mf][0], 0, 0, 0);
      acc[mf][1] = __builtin_amdgcn_mfma_f32_16x16x32_bf16(af, bfr[1], acc[mf][1], 0, 0, 0);
      acc[mf][2] = __builtin_amdgcn_mfma_f32_16x16x32_bf16(af, bfr[2], acc[mf][2], 0, 0, 0);
      acc[mf][3] = __builtin_amdgcn_mfma_f32_16x16x32_bf16(af, bfr[3], acc[mf][3], 0, 0, 0);
    }
    asm volatile("s_waitcnt lgkmcnt(0)" ::: "memory");    // reads done before buffer reuse
    __builtin_amdgcn_s_barrier();
    asm volatile("" ::: "memory");
  }
#undef ISSUE1

  // epilogue: silu(gate)*up; gate cf 0..1, up cf 2..3
  #pragma unroll
  for (int mf = 0; mf < 4; ++mf) {
    #pragma unroll
    for (int g = 0; g < 2; ++g) {
      int fcol = p * 128 + wv * 32 + g * 16 + lr;
      #pragma unroll
      for (int r = 0; r < 4; ++r) {
        int sl = m0 + mf * 16 + lg * 4 + r;
        if (sl < n) {
          float gg = acc[mf][g][r], u = acc[mf][g + 2][r];
          act[(size_t)(sb + sl) * F + fcol] = (unsigned short)f2bf(gg / (1.f + expf(-gg)) * u);
        }
      }
    }
  }
}

// ---------------- ffn2: M=64, N=128, BK=32, K-split x4, gload_lds, DBUF+counted vmcnt ----------------
// Per buffer (20KB): B fp32 [k=32][c=128] rows 512B chunk-swizzled; A bf16 [row=64][k=32]
// rows 64B seg-swizzled. 2 buffers = 40KB -> 4 blocks/CU.
__global__ __launch_bounds__(256, 4) void ffn2_k(
    const unsigned short* __restrict__ act, const float* __restrict__ wd,
    const int* __restrict__ cnt, const int* __restrict__ base,
    const int* __restrict__ gtok, const float* __restrict__ gws,
    float* __restrict__ out)
{
  // 4096 blocks = 8 XCD * 512 (one expert per XCD): 16 mB * 8 p * 4 kh
  int wg = (blockIdx.x & 7) * 512 + (blockIdx.x >> 3);
  int mB = wg & 15;
  int rest = wg >> 4;                // 0..255
  int p = rest & 7;
  int kh = (rest >> 3) & 3;
  int e = rest >> 5;
  int n = cnt[e];
  int m0 = mB * 64;
  if (m0 >= n) return;
  int sb = base[e];
  int tid = threadIdx.x;
  int wv = tid >> 6, lane = tid & 63, lr = lane & 15, lg = lane >> 4;
  const int kbase = kh * 896;

  __shared__ __align__(16) char smem2[40960];
  char* sB0 = smem2;                 // 16KB
  char* sA0 = smem2 + 16384;         // 4KB
  char* sB1 = smem2 + 20480;         // 16KB
  char* sA1 = smem2 + 36864;         // 4KB

  // B staging: wave wv stages k-rows wv*8 .. +8 in 4 issues (2 rows/issue)
  int bchunk = (lane & 31) ^ wv;
  const float* Bsrc = wd + (size_t)e * F * H
                    + (size_t)(kbase + wv * 8 + (lane >> 5)) * H + p * 128 + bchunk * 4;

  // A staging: wave wv stages rows wv*16..+16 in 1 issue (4 lanes/row)
  int arow = wv * 16 + (lane >> 2);
  int aseg = (lane & 3) ^ (arow & 3);
  int asl = m0 + arow; if (asl >= n) asl = n - 1;
  const unsigned short* Asrc = act + (size_t)(sb + asl) * F + kbase + aseg * 8;

  int rboff[2];
  #pragma unroll
  for (int cf = 0; cf < 2; ++cf) {
    int col = wv * 32 + cf * 16 + lr;
    rboff[cf] = lg * 8 * 512 + ((col * 4) ^ (lg << 4));
  }
  int raoff[4];
  #pragma unroll
  for (int mf = 0; mf < 4; ++mf) {
    int row = mf * 16 + lr;
    raoff[mf] = row * 64 + ((lg ^ (row & 3)) << 4);
  }

  f32x4 acc[4][2];
  #pragma unroll
  for (int mf = 0; mf < 4; ++mf) { acc[mf][0] = (f32x4)0.f; acc[mf][1] = (f32x4)0.f; }

#define ISSUE2(S, bB, bA) { \
    const float* bs_ = Bsrc + (size_t)(S) * 32 * H; \
    _Pragma("unroll") for (int j = 0; j < 4; ++j) \
      gload16(bs_ + (size_t)(2 * j) * H, (bB) + (wv * 8 + 2 * j) * 512); \
    gload16(Asrc + (S) * 32, (bA) + wv * 16 * 64); }

  ISSUE2(0, sB0, sA0);

  for (int s = 0; s < 28; ++s) {
    char* cB = (s & 1) ? sB1 : sB0;
    char* cA = (s & 1) ? sA1 : sA0;
    char* nB = (s & 1) ? sB0 : sB1;
    char* nA = (s & 1) ? sA0 : sA1;
    if (s + 1 < 28) {
      ISSUE2(s + 1, nB, nA);
      asm volatile("s_waitcnt vmcnt(5)" ::: "memory");
    } else {
      asm volatile("s_waitcnt vmcnt(0)" ::: "memory");
    }
    __builtin_amdgcn_s_barrier();
    asm volatile("" ::: "memory");

    bf16x8 bfr[2];
    #pragma unroll
    for (int cf = 0; cf < 2; ++cf) {
      float f0 = *(const float*)(cB + rboff[cf]);
      float f1 = *(const float*)(cB + rboff[cf] + 512);
      float f2 = *(const float*)(cB + rboff[cf] + 1024);
      float f3 = *(const float*)(cB + rboff[cf] + 1536);
      float f4 = *(const float*)(cB + rboff[cf] + 2048);
      float f5 = *(const float*)(cB + rboff[cf] + 2560);
      float f6 = *(const float*)(cB + rboff[cf] + 3072);
      float f7 = *(const float*)(cB + rboff[cf] + 3584);
      union { u32x4 u; bf16x8 h; } cv;
      cv.u[0] = pkbf(f0, f1); cv.u[1] = pkbf(f2, f3);
      cv.u[2] = pkbf(f4, f5); cv.u[3] = pkbf(f6, f7);
      bfr[cf] = cv.h;
    }
    #pragma unroll
    for (int mf = 0; mf < 4; ++mf) {
      bf16x8 af = *(const bf16x8*)(cA + raoff[mf]);
      acc[mf][0] = __builtin_amdgcn_mfma_f32_16x16x32_bf16(af, bfr[0], acc[mf][0], 0, 0, 0);
      acc[mf][1] = __builtin_amdgcn_mfma_f32_16x16x32_bf16(af, bfr[1], acc[mf][1], 0, 0, 0);
    }
    asm volatile("s_waitcnt lgkmcnt(0)" ::: "memory");
    __builtin_amdgcn_s_barrier();
    asm volatile("" ::: "memory");
  }
#undef ISSUE2

  #pragma unroll
  for (int mf = 0; mf < 4; ++mf) {
    #pragma unroll
    for (int cf = 0; cf < 2; ++cf) {
      int col = p * 128 + wv * 32 + cf * 16 + lr;
      #pragma unroll
      for (int r = 0; r < 4; ++r) {
        int sl = m0 + mf * 16 + lg * 4 + r;
        if (sl < n) {
          int slot = sb + sl;
          atomicAdd(&out[(size_t)gtok[slot] * H + col], gws[slot] * acc[mf][cf][r]);
        }
      }
    }
  }
}

extern "C" void kernel_launch(void* const* d_in, const int* in_sizes, int n_in,
                              void* d_out, int out_size, void* d_ws, size_t ws_size,
                              hipStream_t stream)
{
  const float* x   = (const float*)d_in[0];
  const float* gw  = (const float*)d_in[1];
  const float* wgu = (const float*)d_in[2];
  const float* wdn = (const float*)d_in[3];
  float* out = (float*)d_out;
  float* logits = out + (size_t)T * H;

  char* w = (char*)d_ws;
  int*   cnt = (int*)(w);
  int*   bs  = (int*)(w + 32);
  int*   te  = (int*)(w + 64);
  int*   tr  = (int*)(w + 64 + 8192);
  float* tw  = (float*)(w + 64 + 16384);
  int*   gt  = (int*)(w + 64 + 24576);
  float* gwt = (float*)(w + 64 + 32768);
  unsigned short* act = (unsigned short*)(w + 65536);  // 2048 x 3584 bf16

  hipMemsetAsync(d_out, 0, (size_t)T * H * sizeof(float), stream);
  hipMemsetAsync(cnt, 0, NE * sizeof(int), stream);
  router_k<<<T, 64, 0, stream>>>(x, gw, logits, cnt, te, tr, tw);
  build_k<<<1, 1024, 0, stream>>>(cnt, bs, te, tr, tw, gt, gwt);
  ffn1_k<<<3584, 256, 0, stream>>>(x, wgu, cnt, bs, gt, act);
  ffn2_k<<<4096, 256, 0, stream>>>(act, wdn, cnt, bs, gt, gwt, out);
}